// Round 18
// baseline (242.344 us; speedup 1.0000x reference)
//
#include <hip/hip_runtime.h>
#include <hip/hip_bf16.h>

// ---------------------------------------------------------------------------
// Primer attention, MI355X.
//  K0 cvt:   w_qkv, w_out fp32 -> bf16 (float4-vectorized)
//  K1 ln:    ChanLayerNorm one-pass (64KB LDS-staged), write xn[b][p][c] bf16
//  K2 gemm:  qkv = w_qkv * xn^T   (128x128 tile, XCD-chunked 1D grid)
//  K3 dw:    depthwise 3x3, d-contiguous LDS + ds_read_b128 (32 ch/block)
//  K4 attn:  R17 champion + bf16 bias table (isolated lever: LDS 40->32.5KB
//            -> 5 blocks/CU). Naive bias index math retained.
//  K5 gemm:  out = w_out * att^T  (128x64 tile)
// ---------------------------------------------------------------------------

typedef __attribute__((ext_vector_type(8))) short bf16x8;
typedef __attribute__((ext_vector_type(4))) float f32x4;
typedef __attribute__((ext_vector_type(8))) unsigned short ushort8;
typedef __attribute__((ext_vector_type(4))) unsigned short us4v;
typedef __attribute__((ext_vector_type(4))) float f32x4v;

#define HEADS 8
#define DHEAD 64
#define NB 16
#define CCH 512
#define NPOS 1024
#define QKV_CH 1536
#define INNER 512
#define THR 4.0f

static __device__ __forceinline__ unsigned short f2bf(float f) {
    unsigned u = __builtin_bit_cast(unsigned, f);
    unsigned r = (u + 0x7fffu + ((u >> 16) & 1u)) >> 16;
    return (unsigned short)r;
}
static __device__ __forceinline__ float bf2f(unsigned short h) {
    unsigned u = ((unsigned)h) << 16;
    return __builtin_bit_cast(float, u);
}

// DPP rotate within 16-lane row: lane i <- lane (i+N) mod 16 of its row.
#define DPP_ROR(v, CTRL)                                                       \
    __builtin_bit_cast(float, __builtin_amdgcn_update_dpp(                     \
        0, __builtin_bit_cast(int, (v)), (CTRL), 0xF, 0xF, true))

#define GLOAD_LDS16(gp, lp)                                                    \
    __builtin_amdgcn_global_load_lds(                                          \
        (const __attribute__((address_space(1))) void*)(gp),                   \
        (__attribute__((address_space(3))) void*)(lp), 16, 0, 0)

// ---------------- K0: weight conversion (vectorized) ----------------
__global__ void cvt_kernel(const float* __restrict__ wqkv, const float* __restrict__ wout,
                           unsigned short* __restrict__ wqkv_bf, unsigned short* __restrict__ wout_bf) {
    int i = blockIdx.x * 256 + threadIdx.x;
    {
        f32x4v v = ((const f32x4v*)wqkv)[i];
        us4v o;
#pragma unroll
        for (int j = 0; j < 4; ++j) o[j] = f2bf(v[j]);
        ((us4v*)wqkv_bf)[i] = o;
    }
    if (i < CCH * INNER / 4) {
        f32x4v v = ((const f32x4v*)wout)[i];
        us4v o;
#pragma unroll
        for (int j = 0; j < 4; ++j) o[j] = f2bf(v[j]);
        ((us4v*)wout_bf)[i] = o;
    }
}

// ---------------- K1: ChanLayerNorm one-pass -> xn_t[b][p][c] bf16 ----------------
__global__ __launch_bounds__(256) void ln_kernel(const float* __restrict__ x,
                                                 const float* __restrict__ gamma,
                                                 unsigned short* __restrict__ xn_t) {
    __shared__ __align__(16) float sX[CCH * 32];   // 64KB: [c][p] for 32 positions
    __shared__ float red[2][8][32];
    __shared__ float stat[2][32];
    const int b = blockIdx.x >> 5;
    const int p0 = (blockIdx.x & 31) * 32;
    const int tid = threadIdx.x, w = tid >> 6, lane = tid & 63;
    const float* xb = x + (size_t)b * CCH * NPOS;
#pragma unroll
    for (int i = 0; i < 16; ++i) {
        int destB = i * 4096 + w * 1024 + lane * 16;
        int c = destB >> 7;
        int colb = destB & 127;
        GLOAD_LDS16(xb + (size_t)c * NPOS + p0 + (colb >> 2), (char*)sX + i * 4096 + w * 1024);
    }
    __syncthreads();
    const int p = tid & 31, cg = tid >> 5;
    float s = 0.f, s2 = 0.f;
#pragma unroll 8
    for (int i = 0; i < 64; ++i) {
        float v = sX[(cg * 64 + i) * 32 + p];
        s += v; s2 += v * v;
    }
    red[0][cg][p] = s; red[1][cg][p] = s2;
    __syncthreads();
    if (tid < 32) {
        float ts = 0.f, t2 = 0.f;
#pragma unroll
        for (int g = 0; g < 8; ++g) { ts += red[0][g][tid]; t2 += red[1][g][tid]; }
        float mean = ts * (1.f / CCH);
        float var = t2 * (1.f / CCH) - mean * mean;
        stat[0][tid] = mean;
        stat[1][tid] = rsqrtf(var + 1e-5f);
    }
    __syncthreads();
    const float mean = stat[0][p], rs = stat[1][p];
    unsigned short* orow = xn_t + ((size_t)(b * NPOS + p0 + p)) * CCH + cg * 64;
#pragma unroll
    for (int c0 = 0; c0 < 64; c0 += 8) {
        ushort8 o;
#pragma unroll
        for (int j = 0; j < 8; ++j) {
            float v = sX[(cg * 64 + c0 + j) * 32 + p];
            o[j] = f2bf((v - mean) * rs * gamma[cg * 64 + c0 + j]);
        }
        *(ushort8*)(orow + c0) = o;
    }
}

// ---------------- K2: batched GEMM 128x128, C[b][m][n] = A[m][k] * Bt[b][n][k] ----------------
template <typename TO>
__global__ __launch_bounds__(256) void gemm_bt(const unsigned short* __restrict__ A,
                                               const unsigned short* __restrict__ Bt,
                                               TO* __restrict__ Cc, int M, int N, int K,
                                               int tilesX, int tilesY) {
    __shared__ __align__(16) unsigned short sA[128 * 64];
    __shared__ __align__(16) unsigned short sB[128 * 64];
    const int tid = threadIdx.x;
    const int w = tid >> 6, lane = tid & 63;
    const int wr = w >> 1, wc = w & 1;
    const int fr = lane & 15, fg = lane >> 4;
    const int nwg = gridDim.x, bid = blockIdx.x;
    const int wgid = (bid & 7) * (nwg >> 3) + (bid >> 3);
    const int tx = wgid % tilesX;
    const int rest = wgid / tilesX;
    const int ty = rest % tilesY;
    const int tz = rest / tilesY;
    const int m0 = ty * 128, n0 = tx * 128;
    const unsigned short* Ab = A + (size_t)m0 * K;
    const unsigned short* Bb = Bt + (size_t)tz * N * K + (size_t)n0 * K;

    f32x4 acc[4][4];
#pragma unroll
    for (int i = 0; i < 4; ++i)
#pragma unroll
        for (int j = 0; j < 4; ++j) acc[i][j] = {0.f, 0.f, 0.f, 0.f};

    for (int k0 = 0; k0 < K; k0 += 64) {
#pragma unroll
        for (int i = 0; i < 4; ++i) {
            int e = i * 2048 + tid * 8;
            int row = e >> 6, col = e & 63;
            GLOAD_LDS16(Ab + (size_t)row * K + k0 + col, sA + i * 2048 + w * 512);
            GLOAD_LDS16(Bb + (size_t)row * K + k0 + col, sB + i * 2048 + w * 512);
        }
        __syncthreads();
#pragma unroll
        for (int ks = 0; ks < 2; ++ks) {
            bf16x8 aF[4], bF[4];
#pragma unroll
            for (int mm = 0; mm < 4; ++mm)
                aF[mm] = *(const bf16x8*)(sA + (wr * 64 + mm * 16 + fr) * 64 + ks * 32 + fg * 8);
#pragma unroll
            for (int nn = 0; nn < 4; ++nn)
                bF[nn] = *(const bf16x8*)(sB + (wc * 64 + nn * 16 + fr) * 64 + ks * 32 + fg * 8);
#pragma unroll
            for (int mm = 0; mm < 4; ++mm)
#pragma unroll
                for (int nn = 0; nn < 4; ++nn)
                    acc[mm][nn] = __builtin_amdgcn_mfma_f32_16x16x32_bf16(aF[mm], bF[nn], acc[mm][nn], 0, 0, 0);
        }
        __syncthreads();
    }
    TO* Cb = Cc + (size_t)tz * M * N;
#pragma unroll
    for (int mm = 0; mm < 4; ++mm) {
#pragma unroll
        for (int j = 0; j < 4; ++j) {
            int r = m0 + wr * 64 + mm * 16 + fg * 4 + j;
#pragma unroll
            for (int nn = 0; nn < 4; ++nn) {
                int c = n0 + wc * 64 + nn * 16 + fr;
                float v = acc[mm][nn][j];
                if constexpr (sizeof(TO) == 2) Cb[(size_t)r * N + c] = f2bf(v);
                else Cb[(size_t)r * N + c] = v;
            }
        }
    }
}

// ---------------- K5: GEMM 128x64 tile (fp32 out) ----------------
__global__ __launch_bounds__(256) void gemm_bt64(const unsigned short* __restrict__ A,
                                                 const unsigned short* __restrict__ Bt,
                                                 float* __restrict__ Cc, int M, int N, int K) {
    __shared__ __align__(16) unsigned short sA[128 * 64];   // 16KB
    __shared__ __align__(16) unsigned short sB[64 * 64];    // 8KB
    const int tid = threadIdx.x;
    const int w = tid >> 6, lane = tid & 63;
    const int fr = lane & 15, fg = lane >> 4;
    const int m0 = blockIdx.y * 128, n0 = blockIdx.x * 64;
    const unsigned short* Ab = A + (size_t)m0 * K;
    const unsigned short* Bb = Bt + (size_t)blockIdx.z * N * K + (size_t)n0 * K;

    f32x4 acc[2][4];
#pragma unroll
    for (int i = 0; i < 2; ++i)
#pragma unroll
        for (int j = 0; j < 4; ++j) acc[i][j] = {0.f, 0.f, 0.f, 0.f};

    for (int k0 = 0; k0 < K; k0 += 64) {
#pragma unroll
        for (int i = 0; i < 4; ++i) {
            int e = i * 2048 + tid * 8;
            int row = e >> 6, col = e & 63;
            GLOAD_LDS16(Ab + (size_t)row * K + k0 + col, sA + i * 2048 + w * 512);
        }
#pragma unroll
        for (int i = 0; i < 2; ++i) {
            int e = i * 2048 + tid * 8;
            int row = e >> 6, col = e & 63;
            GLOAD_LDS16(Bb + (size_t)row * K + k0 + col, sB + i * 2048 + w * 512);
        }
        __syncthreads();
#pragma unroll
        for (int ks = 0; ks < 2; ++ks) {
            bf16x8 aF[2], bF[4];
#pragma unroll
            for (int mm = 0; mm < 2; ++mm)
                aF[mm] = *(const bf16x8*)(sA + (w * 32 + mm * 16 + fr) * 64 + ks * 32 + fg * 8);
#pragma unroll
            for (int nn = 0; nn < 4; ++nn)
                bF[nn] = *(const bf16x8*)(sB + (nn * 16 + fr) * 64 + ks * 32 + fg * 8);
#pragma unroll
            for (int mm = 0; mm < 2; ++mm)
#pragma unroll
                for (int nn = 0; nn < 4; ++nn)
                    acc[mm][nn] = __builtin_amdgcn_mfma_f32_16x16x32_bf16(aF[mm], bF[nn], acc[mm][nn], 0, 0, 0);
        }
        __syncthreads();
    }
    float* Cb = Cc + (size_t)blockIdx.z * M * N;
#pragma unroll
    for (int mm = 0; mm < 2; ++mm) {
#pragma unroll
        for (int j = 0; j < 4; ++j) {
            int r = m0 + w * 32 + mm * 16 + fg * 4 + j;
#pragma unroll
            for (int nn = 0; nn < 4; ++nn) {
                int c = n0 + nn * 16 + fr;
                Cb[(size_t)r * N + c] = acc[mm][nn][j];
            }
        }
    }
}

// ---------------- K3: depthwise 3x3, d-contiguous LDS, vectorized reads ----------------
__global__ __launch_bounds__(256) void dwconv_kernel(const unsigned short* __restrict__ qkv,
                              const float* __restrict__ wq, const float* __restrict__ bq,
                              const float* __restrict__ wk, const float* __restrict__ bk,
                              const float* __restrict__ wv, const float* __restrict__ bv,
                              unsigned short* __restrict__ qa, unsigned short* __restrict__ ka,
                              unsigned short* __restrict__ vt) {
    // [chunk(4)][row(10)][x(34: -1..32 padded)][d(8)] bf16 = 21.25KB
    __shared__ __align__(16) unsigned short sIn[4 * 10 * 34 * 8];
    __shared__ __align__(16) float wS[9][32];   // [tap][dloc]
    __shared__ float bS[32];
    const int yt = blockIdx.x & 3;
    const int chalf = (blockIdx.x >> 2) & 1;
    const int hw = blockIdx.x >> 3;          // which*8 + h
    const int which = hw >> 3, h = hw & 7;
    const int b = blockIdx.y;
    const int y0 = yt * 8;
    const float* wsel = which == 0 ? wq : which == 1 ? wk : wv;
    const float* bsel = which == 0 ? bq : which == 1 ? bk : bv;
    const int ocbase = which * 512 + h * 64 + chalf * 32;
    const int tid = threadIdx.x;

    for (int i = tid; i < 288; i += 256) {
        int dloc = i / 9, k = i % 9;
        wS[k][dloc] = wsel[(size_t)(h * 64 + chalf * 32 + dloc) * 9 + k];
    }
    if (tid < 32) bS[tid] = bsel[h * 64 + chalf * 32 + tid];

    const unsigned short* src = qkv + ((size_t)b * QKV_CH + ocbase) * NPOS;
#pragma unroll
    for (int it = 0; it < 5; ++it) {
        int idx = it * 256 + tid;            // 1280 = 32ch * 10rows * 4 qwords
        int ch = idx / 40, rem = idx % 40;
        int j = rem >> 2, q = rem & 3;
        int yy = y0 - 1 + j;
        ushort8 v = {0, 0, 0, 0, 0, 0, 0, 0};
        if (yy >= 0 && yy < 32) v = *(const ushort8*)(src + (size_t)ch * NPOS + yy * 32 + q * 8);
        unsigned short* d0 = sIn + (((ch >> 3) * 10 + j) * 34 + (q * 8 + 1)) * 8 + (ch & 7);
#pragma unroll
        for (int e = 0; e < 8; ++e) d0[e * 8] = v[e];
    }
    {
        ushort8 z = {0, 0, 0, 0, 0, 0, 0, 0};
        for (int i = tid; i < 80; i += 256) {
            int c = i / 20, rr = i % 20;
            int j = rr >> 1, side = rr & 1;
            *(ushort8*)(sIn + ((c * 10 + j) * 34 + (side ? 33 : 0)) * 8) = z;
        }
    }
    __syncthreads();

    const int r = tid >> 5, xx = tid & 31;
    const float scale = which == 0 ? 0.125f : 1.f;
#pragma unroll
    for (int c = 0; c < 4; ++c) {
        float acc[8];
#pragma unroll
        for (int dd = 0; dd < 8; ++dd) acc[dd] = bS[c * 8 + dd];
#pragma unroll
        for (int dy = 0; dy < 3; ++dy) {
#pragma unroll
            for (int dx = 0; dx < 3; ++dx) {
                ushort8 v = *(const ushort8*)(sIn + ((c * 10 + r + dy) * 34 + xx + dx) * 8);
#pragma unroll
                for (int dd = 0; dd < 8; ++dd)
                    acc[dd] += wS[dy * 3 + dx][c * 8 + dd] * bf2f(v[dd]);
            }
        }
        ushort8 ob;
#pragma unroll
        for (int dd = 0; dd < 8; ++dd) ob[dd] = f2bf(acc[dd] * scale);
        const int p = (y0 + r) * 32 + xx;
        if (which == 2) {
#pragma unroll
            for (int dd = 0; dd < 8; ++dd)
                vt[((size_t)(b * HEADS + h) * DHEAD + chalf * 32 + c * 8 + dd) * NPOS + p] = ob[dd];
        } else {
            unsigned short* dst = (which == 0 ? qa : ka) +
                ((size_t)(b * HEADS + h) * NPOS + p) * DHEAD + chalf * 32 + c * 8;
            *(ushort8*)dst = ob;
        }
    }
}

// ---------------- K4: flash attention, R17 + bf16 bias table (32.5KB LDS) ----------------
__global__ __launch_bounds__(256) void attn_kernel(const unsigned short* __restrict__ qa,
                                                   const unsigned short* __restrict__ ka,
                                                   const unsigned short* __restrict__ vt,
                                                   const float* __restrict__ pos_emb,
                                                   unsigned short* __restrict__ att_t) {
    __shared__ unsigned short bias_s[3970];                  // bf16, 7.75KB
    __shared__ __align__(16) unsigned short kT[64 * 64];     // 8KB
    __shared__ __align__(16) unsigned short vT[64 * 64];     // 8KB
    __shared__ __align__(16) unsigned short pS[4 * 16 * 64]; // 8KB => 32.5KB total
    const int tid = threadIdx.x, w = tid >> 6, lane = tid & 63;
    const int fr = lane & 15, fg = lane >> 4;
    const int qb = blockIdx.x, h = blockIdx.y, b = blockIdx.z;
    const int bh = b * HEADS + h;
    const unsigned short* qbase = qa + (size_t)bh * NPOS * DHEAD;
    const unsigned short* kbase = ka + (size_t)bh * NPOS * DHEAD;
    const unsigned short* vbase = vt + (size_t)bh * DHEAD * NPOS;

    for (int i = tid; i < 3969; i += 256) bias_s[i] = f2bf(pos_emb[i * HEADS + h]);

    const int i0 = qb * 64 + w * 16;
    bf16x8 aQ[2];
#pragma unroll
    for (int ks = 0; ks < 2; ++ks)
        aQ[ks] = *(const bf16x8*)(qbase + (size_t)(i0 + fr) * DHEAD + ks * 32 + fg * 8);

    // T14 staging addresses (pre-swizzled global source; linear LDS dest)
    const int dB0 = w * 1024 + lane * 16;          // bytes [0, 4096)
    const int dB1 = 4096 + w * 1024 + lane * 16;   // bytes [4096, 8192)
    const int row0 = dB0 >> 7, row1 = dB1 >> 7;
    const int col0 = ((dB0 & 127) ^ ((row0 & 7) << 4)) >> 1;
    const int col1 = ((dB1 & 127) ^ ((row1 & 7) << 4)) >> 1;

    // prologue: tile 0 -> registers
    bf16x8 rk0 = *(const bf16x8*)(kbase + (size_t)row0 * DHEAD + col0);
    bf16x8 rk1 = *(const bf16x8*)(kbase + (size_t)row1 * DHEAD + col1);
    bf16x8 rv0 = *(const bf16x8*)(vbase + (size_t)row0 * NPOS + col0);
    bf16x8 rv1 = *(const bf16x8*)(vbase + (size_t)row1 * NPOS + col1);

    float m[4], l[4];
    f32x4 o[4];
#pragma unroll
    for (int j = 0; j < 4; ++j) { m[j] = -1e30f; l[j] = 0.f; }
#pragma unroll
    for (int dn = 0; dn < 4; ++dn) o[dn] = {0.f, 0.f, 0.f, 0.f};

    __syncthreads();  // bias_s ready; kT/vT unused yet

    for (int t = 0; t < 16; ++t) {
        const int kv0 = t * 64;
        // write staged regs -> LDS
        *(bf16x8*)((char*)kT + dB0) = rk0;
        *(bf16x8*)((char*)kT + dB1) = rk1;
        *(bf16x8*)((char*)vT + dB0) = rv0;
        *(bf16x8*)((char*)vT + dB1) = rv1;
        // issue NEXT tile's global loads; latency hides under this tile's compute
        if (t < 15) {
            const int kv1 = kv0 + 64;
            rk0 = *(const bf16x8*)(kbase + (size_t)(kv1 + row0) * DHEAD + col0);
            rk1 = *(const bf16x8*)(kbase + (size_t)(kv1 + row1) * DHEAD + col1);
            rv0 = *(const bf16x8*)(vbase + (size_t)row0 * NPOS + kv1 + col0);
            rv1 = *(const bf16x8*)(vbase + (size_t)row1 * NPOS + kv1 + col1);
        }
        __syncthreads();  // staged writes visible to all waves

        f32x4 s[4];
#pragma unroll
        for (int nn = 0; nn < 4; ++nn) s[nn] = {0.f, 0.f, 0.f, 0.f};
#pragma unroll
        for (int ks = 0; ks < 2; ++ks) {
#pragma unroll
            for (int nn = 0; nn < 4; ++nn) {
                unsigned kb = (unsigned)(((nn * 16 + fr) * 64 + ks * 32 + fg * 8) * 2);
                kb ^= ((kb >> 7) & 7) << 4;
                bf16x8 bK = *(const bf16x8*)((const char*)kT + kb);
                s[nn] = __builtin_amdgcn_mfma_f32_16x16x32_bf16(aQ[ks], bK, s[nn], 0, 0, 0);
            }
        }
        // bias + tile max (row r = i0 + fg*4 + j, col = kv0 + nn*16 + fr)
        float tmax[4];
#pragma unroll
        for (int j = 0; j < 4; ++j) {
            int iglob = i0 + fg * 4 + j;
            int yi = iglob >> 5, xi = iglob & 31;
            float tm = -1e30f;
#pragma unroll
            for (int nn = 0; nn < 4; ++nn) {
                int jglob = kv0 + nn * 16 + fr;
                int yj = jglob >> 5, xj = jglob & 31;
                int bidx = (yi - yj + 31) * 63 + (xi - xj + 31);
                s[nn][j] += bf2f(bias_s[bidx]);
                tm = fmaxf(tm, s[nn][j]);
            }
            tm = fmaxf(tm, DPP_ROR(tm, 0x121));   // ror:1
            tm = fmaxf(tm, DPP_ROR(tm, 0x122));   // ror:2
            tm = fmaxf(tm, DPP_ROR(tm, 0x124));   // ror:4
            tm = fmaxf(tm, DPP_ROR(tm, 0x128));   // ror:8
            tmax[j] = tm;
        }
        // T13 defer-max: rescale only when some row max grows past THR
        bool grow = (tmax[0] > m[0] + THR) | (tmax[1] > m[1] + THR) |
                    (tmax[2] > m[2] + THR) | (tmax[3] > m[3] + THR);
        if (__any(grow)) {
#pragma unroll
            for (int j = 0; j < 4; ++j) {
                float pm = fmaxf(m[j], tmax[j]);
                float alpha = __expf(m[j] - pm);
                m[j] = pm;
                l[j] *= alpha;
#pragma unroll
                for (int dn = 0; dn < 4; ++dn) o[dn][j] *= alpha;
            }
        }
#pragma unroll
        for (int j = 0; j < 4; ++j) {
            float rsum = 0.f;
#pragma unroll
            for (int nn = 0; nn < 4; ++nn) {
                float pv = __expf(s[nn][j] - m[j]);
                s[nn][j] = pv;
                rsum += pv;
            }
            rsum += DPP_ROR(rsum, 0x121);
            rsum += DPP_ROR(rsum, 0x122);
            rsum += DPP_ROR(rsum, 0x124);
            rsum += DPP_ROR(rsum, 0x128);
            l[j] += rsum;
        }
        // P -> LDS (C/D layout -> A-operand layout), swizzled, wave-private
#pragma unroll
        for (int j = 0; j < 4; ++j) {
            int rrow = fg * 4 + j;
#pragma unroll
            for (int nn = 0; nn < 4; ++nn) {
                unsigned pb = (unsigned)((w * 16 + rrow) * 128 + (nn * 16 + fr) * 2);
                pb ^= ((pb >> 7) & 7) << 4;
                *(unsigned short*)((char*)pS + pb) = f2bf(s[nn][j]);
            }
        }
        // PV
#pragma unroll
        for (int ks = 0; ks < 2; ++ks) {
            unsigned pb = (unsigned)((w * 16 + fr) * 128 + (ks * 32 + fg * 8) * 2);
            pb ^= ((pb >> 7) & 7) << 4;
            bf16x8 aP = *(const bf16x8*)((const char*)pS + pb);
#pragma unroll
            for (int dn = 0; dn < 4; ++dn) {
                unsigned vb = (unsigned)(((dn * 16 + fr) * 64 + ks * 32 + fg * 8) * 2);
                vb ^= ((vb >> 7) & 7) << 4;
                bf16x8 bV = *(const bf16x8*)((const char*)vT + vb);
                o[dn] = __builtin_amdgcn_mfma_f32_16x16x32_bf16(aP, bV, o[dn], 0, 0, 0);
            }
        }
        __syncthreads();  // all waves done reading kT/vT before next overwrite
    }
    // epilogue: att_t[b][i][h*64+d] bf16
#pragma unroll
    for (int j = 0; j < 4; ++j) {
        float inv = 1.f / l[j];
        int iglob = i0 + fg * 4 + j;
        unsigned short* orow = att_t + ((size_t)b * NPOS + iglob) * INNER + h * DHEAD;
#pragma unroll
        for (int dn = 0; dn < 4; ++dn) orow[dn * 16 + fr] = f2bf(o[dn][j] * inv);
    }
}

// ---------------------------------------------------------------------------
extern "C" void kernel_launch(void* const* d_in, const int* in_sizes, int n_in,
                              void* d_out, int out_size, void* d_ws, size_t ws_size,
                              hipStream_t stream) {
    const float* x      = (const float*)d_in[0];
    const float* gamma  = (const float*)d_in[1];
    const float* w_qkv  = (const float*)d_in[2];
    const float* dw_w_q = (const float*)d_in[3];
    const float* dw_b_q = (const float*)d_in[4];
    const float* dw_w_k = (const float*)d_in[5];
    const float* dw_b_k = (const float*)d_in[6];
    const float* dw_w_v = (const float*)d_in[7];
    const float* dw_b_v = (const float*)d_in[8];
    const float* w_out  = (const float*)d_in[9];
    const float* pos_emb = (const float*)d_in[10];
    float* out = (float*)d_out;
    char* ws = (char*)d_ws;

    const size_t MB = 1024 * 1024;
    unsigned short* wqkv_bf = (unsigned short*)(ws + 0);              // 1.5MB
    unsigned short* wout_bf = (unsigned short*)(ws + 1536 * 512 * 2); // 0.5MB -> ends 2MB
    unsigned short* xn_t    = (unsigned short*)(ws + 2 * MB);         // 16MB [2,18)
    unsigned short* qkv     = (unsigned short*)(ws + 18 * MB);        // 48MB [18,66)
    unsigned short* qa      = (unsigned short*)(ws + 66 * MB);        // 16MB [66,82)
    unsigned short* kb      = (unsigned short*)(ws + 82 * MB);        // 16MB [82,98)
    unsigned short* vt      = (unsigned short*)(ws + 2 * MB);         // reuse xn (dead after K2)
    unsigned short* att_t   = (unsigned short*)(ws + 18 * MB);        // reuse qkv (dead after K3)

    cvt_kernel<<<dim3(768), dim3(256), 0, stream>>>(w_qkv, w_out, wqkv_bf, wout_bf);
    ln_kernel<<<dim3(512), dim3(256), 0, stream>>>(x, gamma, xn_t);
    gemm_bt<unsigned short><<<dim3(1536), dim3(256), 0, stream>>>(wqkv_bf, xn_t, qkv,
                                                                  1536, 1024, 512, 8, 12);
    dwconv_kernel<<<dim3(192, 16), dim3(256), 0, stream>>>(qkv, dw_w_q, dw_b_q, dw_w_k, dw_b_k,
                                                           dw_w_v, dw_b_v, qa, kb, vt);
    attn_kernel<<<dim3(16, 8, 16), dim3(256), 0, stream>>>(qa, kb, vt, pos_emb, att_t);
    gemm_bt64<<<dim3(16, 4, 16), dim3(256), 0, stream>>>(wout_bf, att_t, out, 512, 1024, 512);
}

// Round 19
// 210.781 us; speedup vs baseline: 1.1497x; 1.1497x over previous
//
#include <hip/hip_runtime.h>
#include <hip/hip_bf16.h>

// ---------------------------------------------------------------------------
// Primer attention, MI355X — FINAL (R17 champion).
//  K0 cvt:   w_qkv, w_out fp32 -> bf16 (float4-vectorized)
//  K1 ln:    ChanLayerNorm one-pass (64KB LDS-staged), write xn[b][p][c] bf16
//  K2 gemm:  qkv = w_qkv * xn^T   (128x128 tile, XCD-chunked 1D grid)
//  K3 dw:    depthwise 3x3, d-contiguous LDS + ds_read_b128 (32 ch/block)
//  K4 attn:  64-row Q tile, 256 thr, XOR-swizzled kT/vT/pS, T14 async-STAGE,
//            fp32 bias table (bf16 gather = +35us stall, 4x reproduced),
//            DPP row_ror reductions, defer-max. 112us, VGPR 80.
//  K5 gemm:  out = w_out * att^T  (128x64 tile)
// ---------------------------------------------------------------------------

typedef __attribute__((ext_vector_type(8))) short bf16x8;
typedef __attribute__((ext_vector_type(4))) float f32x4;
typedef __attribute__((ext_vector_type(8))) unsigned short ushort8;
typedef __attribute__((ext_vector_type(4))) unsigned short us4v;
typedef __attribute__((ext_vector_type(4))) float f32x4v;

#define HEADS 8
#define DHEAD 64
#define NB 16
#define CCH 512
#define NPOS 1024
#define QKV_CH 1536
#define INNER 512
#define THR 4.0f

static __device__ __forceinline__ unsigned short f2bf(float f) {
    unsigned u = __builtin_bit_cast(unsigned, f);
    unsigned r = (u + 0x7fffu + ((u >> 16) & 1u)) >> 16;
    return (unsigned short)r;
}
static __device__ __forceinline__ float bf2f(unsigned short h) {
    unsigned u = ((unsigned)h) << 16;
    return __builtin_bit_cast(float, u);
}

// DPP rotate within 16-lane row: lane i <- lane (i+N) mod 16 of its row.
#define DPP_ROR(v, CTRL)                                                       \
    __builtin_bit_cast(float, __builtin_amdgcn_update_dpp(                     \
        0, __builtin_bit_cast(int, (v)), (CTRL), 0xF, 0xF, true))

#define GLOAD_LDS16(gp, lp)                                                    \
    __builtin_amdgcn_global_load_lds(                                          \
        (const __attribute__((address_space(1))) void*)(gp),                   \
        (__attribute__((address_space(3))) void*)(lp), 16, 0, 0)

// ---------------- K0: weight conversion (vectorized) ----------------
__global__ void cvt_kernel(const float* __restrict__ wqkv, const float* __restrict__ wout,
                           unsigned short* __restrict__ wqkv_bf, unsigned short* __restrict__ wout_bf) {
    int i = blockIdx.x * 256 + threadIdx.x;
    {
        f32x4v v = ((const f32x4v*)wqkv)[i];
        us4v o;
#pragma unroll
        for (int j = 0; j < 4; ++j) o[j] = f2bf(v[j]);
        ((us4v*)wqkv_bf)[i] = o;
    }
    if (i < CCH * INNER / 4) {
        f32x4v v = ((const f32x4v*)wout)[i];
        us4v o;
#pragma unroll
        for (int j = 0; j < 4; ++j) o[j] = f2bf(v[j]);
        ((us4v*)wout_bf)[i] = o;
    }
}

// ---------------- K1: ChanLayerNorm one-pass -> xn_t[b][p][c] bf16 ----------------
__global__ __launch_bounds__(256) void ln_kernel(const float* __restrict__ x,
                                                 const float* __restrict__ gamma,
                                                 unsigned short* __restrict__ xn_t) {
    __shared__ __align__(16) float sX[CCH * 32];   // 64KB: [c][p] for 32 positions
    __shared__ float red[2][8][32];
    __shared__ float stat[2][32];
    const int b = blockIdx.x >> 5;
    const int p0 = (blockIdx.x & 31) * 32;
    const int tid = threadIdx.x, w = tid >> 6, lane = tid & 63;
    const float* xb = x + (size_t)b * CCH * NPOS;
#pragma unroll
    for (int i = 0; i < 16; ++i) {
        int destB = i * 4096 + w * 1024 + lane * 16;
        int c = destB >> 7;
        int colb = destB & 127;
        GLOAD_LDS16(xb + (size_t)c * NPOS + p0 + (colb >> 2), (char*)sX + i * 4096 + w * 1024);
    }
    __syncthreads();
    const int p = tid & 31, cg = tid >> 5;
    float s = 0.f, s2 = 0.f;
#pragma unroll 8
    for (int i = 0; i < 64; ++i) {
        float v = sX[(cg * 64 + i) * 32 + p];
        s += v; s2 += v * v;
    }
    red[0][cg][p] = s; red[1][cg][p] = s2;
    __syncthreads();
    if (tid < 32) {
        float ts = 0.f, t2 = 0.f;
#pragma unroll
        for (int g = 0; g < 8; ++g) { ts += red[0][g][tid]; t2 += red[1][g][tid]; }
        float mean = ts * (1.f / CCH);
        float var = t2 * (1.f / CCH) - mean * mean;
        stat[0][tid] = mean;
        stat[1][tid] = rsqrtf(var + 1e-5f);
    }
    __syncthreads();
    const float mean = stat[0][p], rs = stat[1][p];
    unsigned short* orow = xn_t + ((size_t)(b * NPOS + p0 + p)) * CCH + cg * 64;
#pragma unroll
    for (int c0 = 0; c0 < 64; c0 += 8) {
        ushort8 o;
#pragma unroll
        for (int j = 0; j < 8; ++j) {
            float v = sX[(cg * 64 + c0 + j) * 32 + p];
            o[j] = f2bf((v - mean) * rs * gamma[cg * 64 + c0 + j]);
        }
        *(ushort8*)(orow + c0) = o;
    }
}

// ---------------- K2: batched GEMM 128x128, C[b][m][n] = A[m][k] * Bt[b][n][k] ----------------
template <typename TO>
__global__ __launch_bounds__(256) void gemm_bt(const unsigned short* __restrict__ A,
                                               const unsigned short* __restrict__ Bt,
                                               TO* __restrict__ Cc, int M, int N, int K,
                                               int tilesX, int tilesY) {
    __shared__ __align__(16) unsigned short sA[128 * 64];
    __shared__ __align__(16) unsigned short sB[128 * 64];
    const int tid = threadIdx.x;
    const int w = tid >> 6, lane = tid & 63;
    const int wr = w >> 1, wc = w & 1;
    const int fr = lane & 15, fg = lane >> 4;
    const int nwg = gridDim.x, bid = blockIdx.x;
    const int wgid = (bid & 7) * (nwg >> 3) + (bid >> 3);
    const int tx = wgid % tilesX;
    const int rest = wgid / tilesX;
    const int ty = rest % tilesY;
    const int tz = rest / tilesY;
    const int m0 = ty * 128, n0 = tx * 128;
    const unsigned short* Ab = A + (size_t)m0 * K;
    const unsigned short* Bb = Bt + (size_t)tz * N * K + (size_t)n0 * K;

    f32x4 acc[4][4];
#pragma unroll
    for (int i = 0; i < 4; ++i)
#pragma unroll
        for (int j = 0; j < 4; ++j) acc[i][j] = {0.f, 0.f, 0.f, 0.f};

    for (int k0 = 0; k0 < K; k0 += 64) {
#pragma unroll
        for (int i = 0; i < 4; ++i) {
            int e = i * 2048 + tid * 8;
            int row = e >> 6, col = e & 63;
            GLOAD_LDS16(Ab + (size_t)row * K + k0 + col, sA + i * 2048 + w * 512);
            GLOAD_LDS16(Bb + (size_t)row * K + k0 + col, sB + i * 2048 + w * 512);
        }
        __syncthreads();
#pragma unroll
        for (int ks = 0; ks < 2; ++ks) {
            bf16x8 aF[4], bF[4];
#pragma unroll
            for (int mm = 0; mm < 4; ++mm)
                aF[mm] = *(const bf16x8*)(sA + (wr * 64 + mm * 16 + fr) * 64 + ks * 32 + fg * 8);
#pragma unroll
            for (int nn = 0; nn < 4; ++nn)
                bF[nn] = *(const bf16x8*)(sB + (wc * 64 + nn * 16 + fr) * 64 + ks * 32 + fg * 8);
#pragma unroll
            for (int mm = 0; mm < 4; ++mm)
#pragma unroll
                for (int nn = 0; nn < 4; ++nn)
                    acc[mm][nn] = __builtin_amdgcn_mfma_f32_16x16x32_bf16(aF[mm], bF[nn], acc[mm][nn], 0, 0, 0);
        }
        __syncthreads();
    }
    TO* Cb = Cc + (size_t)tz * M * N;
#pragma unroll
    for (int mm = 0; mm < 4; ++mm) {
#pragma unroll
        for (int j = 0; j < 4; ++j) {
            int r = m0 + wr * 64 + mm * 16 + fg * 4 + j;
#pragma unroll
            for (int nn = 0; nn < 4; ++nn) {
                int c = n0 + wc * 64 + nn * 16 + fr;
                float v = acc[mm][nn][j];
                if constexpr (sizeof(TO) == 2) Cb[(size_t)r * N + c] = f2bf(v);
                else Cb[(size_t)r * N + c] = v;
            }
        }
    }
}

// ---------------- K5: GEMM 128x64 tile (fp32 out) ----------------
__global__ __launch_bounds__(256) void gemm_bt64(const unsigned short* __restrict__ A,
                                                 const unsigned short* __restrict__ Bt,
                                                 float* __restrict__ Cc, int M, int N, int K) {
    __shared__ __align__(16) unsigned short sA[128 * 64];   // 16KB
    __shared__ __align__(16) unsigned short sB[64 * 64];    // 8KB
    const int tid = threadIdx.x;
    const int w = tid >> 6, lane = tid & 63;
    const int fr = lane & 15, fg = lane >> 4;
    const int m0 = blockIdx.y * 128, n0 = blockIdx.x * 64;
    const unsigned short* Ab = A + (size_t)m0 * K;
    const unsigned short* Bb = Bt + (size_t)blockIdx.z * N * K + (size_t)n0 * K;

    f32x4 acc[2][4];
#pragma unroll
    for (int i = 0; i < 2; ++i)
#pragma unroll
        for (int j = 0; j < 4; ++j) acc[i][j] = {0.f, 0.f, 0.f, 0.f};

    for (int k0 = 0; k0 < K; k0 += 64) {
#pragma unroll
        for (int i = 0; i < 4; ++i) {
            int e = i * 2048 + tid * 8;
            int row = e >> 6, col = e & 63;
            GLOAD_LDS16(Ab + (size_t)row * K + k0 + col, sA + i * 2048 + w * 512);
        }
#pragma unroll
        for (int i = 0; i < 2; ++i) {
            int e = i * 2048 + tid * 8;
            int row = e >> 6, col = e & 63;
            GLOAD_LDS16(Bb + (size_t)row * K + k0 + col, sB + i * 2048 + w * 512);
        }
        __syncthreads();
#pragma unroll
        for (int ks = 0; ks < 2; ++ks) {
            bf16x8 aF[2], bF[4];
#pragma unroll
            for (int mm = 0; mm < 2; ++mm)
                aF[mm] = *(const bf16x8*)(sA + (w * 32 + mm * 16 + fr) * 64 + ks * 32 + fg * 8);
#pragma unroll
            for (int nn = 0; nn < 4; ++nn)
                bF[nn] = *(const bf16x8*)(sB + (nn * 16 + fr) * 64 + ks * 32 + fg * 8);
#pragma unroll
            for (int mm = 0; mm < 2; ++mm)
#pragma unroll
                for (int nn = 0; nn < 4; ++nn)
                    acc[mm][nn] = __builtin_amdgcn_mfma_f32_16x16x32_bf16(aF[mm], bF[nn], acc[mm][nn], 0, 0, 0);
        }
        __syncthreads();
    }
    float* Cb = Cc + (size_t)blockIdx.z * M * N;
#pragma unroll
    for (int mm = 0; mm < 2; ++mm) {
#pragma unroll
        for (int j = 0; j < 4; ++j) {
            int r = m0 + w * 32 + mm * 16 + fg * 4 + j;
#pragma unroll
            for (int nn = 0; nn < 4; ++nn) {
                int c = n0 + nn * 16 + fr;
                Cb[(size_t)r * N + c] = acc[mm][nn][j];
            }
        }
    }
}

// ---------------- K3: depthwise 3x3, d-contiguous LDS, vectorized reads ----------------
__global__ __launch_bounds__(256) void dwconv_kernel(const unsigned short* __restrict__ qkv,
                              const float* __restrict__ wq, const float* __restrict__ bq,
                              const float* __restrict__ wk, const float* __restrict__ bk,
                              const float* __restrict__ wv, const float* __restrict__ bv,
                              unsigned short* __restrict__ qa, unsigned short* __restrict__ ka,
                              unsigned short* __restrict__ vt) {
    // [chunk(4)][row(10)][x(34: -1..32 padded)][d(8)] bf16 = 21.25KB
    __shared__ __align__(16) unsigned short sIn[4 * 10 * 34 * 8];
    __shared__ __align__(16) float wS[9][32];   // [tap][dloc]
    __shared__ float bS[32];
    const int yt = blockIdx.x & 3;
    const int chalf = (blockIdx.x >> 2) & 1;
    const int hw = blockIdx.x >> 3;          // which*8 + h
    const int which = hw >> 3, h = hw & 7;
    const int b = blockIdx.y;
    const int y0 = yt * 8;
    const float* wsel = which == 0 ? wq : which == 1 ? wk : wv;
    const float* bsel = which == 0 ? bq : which == 1 ? bk : bv;
    const int ocbase = which * 512 + h * 64 + chalf * 32;
    const int tid = threadIdx.x;

    for (int i = tid; i < 288; i += 256) {
        int dloc = i / 9, k = i % 9;
        wS[k][dloc] = wsel[(size_t)(h * 64 + chalf * 32 + dloc) * 9 + k];
    }
    if (tid < 32) bS[tid] = bsel[h * 64 + chalf * 32 + tid];

    const unsigned short* src = qkv + ((size_t)b * QKV_CH + ocbase) * NPOS;
#pragma unroll
    for (int it = 0; it < 5; ++it) {
        int idx = it * 256 + tid;            // 1280 = 32ch * 10rows * 4 qwords
        int ch = idx / 40, rem = idx % 40;
        int j = rem >> 2, q = rem & 3;
        int yy = y0 - 1 + j;
        ushort8 v = {0, 0, 0, 0, 0, 0, 0, 0};
        if (yy >= 0 && yy < 32) v = *(const ushort8*)(src + (size_t)ch * NPOS + yy * 32 + q * 8);
        unsigned short* d0 = sIn + (((ch >> 3) * 10 + j) * 34 + (q * 8 + 1)) * 8 + (ch & 7);
#pragma unroll
        for (int e = 0; e < 8; ++e) d0[e * 8] = v[e];
    }
    {
        ushort8 z = {0, 0, 0, 0, 0, 0, 0, 0};
        for (int i = tid; i < 80; i += 256) {
            int c = i / 20, rr = i % 20;
            int j = rr >> 1, side = rr & 1;
            *(ushort8*)(sIn + ((c * 10 + j) * 34 + (side ? 33 : 0)) * 8) = z;
        }
    }
    __syncthreads();

    const int r = tid >> 5, xx = tid & 31;
    const float scale = which == 0 ? 0.125f : 1.f;
#pragma unroll
    for (int c = 0; c < 4; ++c) {
        float acc[8];
#pragma unroll
        for (int dd = 0; dd < 8; ++dd) acc[dd] = bS[c * 8 + dd];
#pragma unroll
        for (int dy = 0; dy < 3; ++dy) {
#pragma unroll
            for (int dx = 0; dx < 3; ++dx) {
                ushort8 v = *(const ushort8*)(sIn + ((c * 10 + r + dy) * 34 + xx + dx) * 8);
#pragma unroll
                for (int dd = 0; dd < 8; ++dd)
                    acc[dd] += wS[dy * 3 + dx][c * 8 + dd] * bf2f(v[dd]);
            }
        }
        ushort8 ob;
#pragma unroll
        for (int dd = 0; dd < 8; ++dd) ob[dd] = f2bf(acc[dd] * scale);
        const int p = (y0 + r) * 32 + xx;
        if (which == 2) {
#pragma unroll
            for (int dd = 0; dd < 8; ++dd)
                vt[((size_t)(b * HEADS + h) * DHEAD + chalf * 32 + c * 8 + dd) * NPOS + p] = ob[dd];
        } else {
            unsigned short* dst = (which == 0 ? qa : ka) +
                ((size_t)(b * HEADS + h) * NPOS + p) * DHEAD + chalf * 32 + c * 8;
            *(ushort8*)dst = ob;
        }
    }
}

// ---------------- K4: flash attention, champion (fp32 bias + defer-max) ----------------
__global__ __launch_bounds__(256) void attn_kernel(const unsigned short* __restrict__ qa,
                                                   const unsigned short* __restrict__ ka,
                                                   const unsigned short* __restrict__ vt,
                                                   const float* __restrict__ pos_emb,
                                                   unsigned short* __restrict__ att_t) {
    __shared__ float bias_s[3969];
    __shared__ __align__(16) unsigned short kT[64 * 64];
    __shared__ __align__(16) unsigned short vT[64 * 64];
    __shared__ __align__(16) unsigned short pS[4 * 16 * 64];
    const int tid = threadIdx.x, w = tid >> 6, lane = tid & 63;
    const int fr = lane & 15, fg = lane >> 4;
    const int qb = blockIdx.x, h = blockIdx.y, b = blockIdx.z;
    const int bh = b * HEADS + h;
    const unsigned short* qbase = qa + (size_t)bh * NPOS * DHEAD;
    const unsigned short* kbase = ka + (size_t)bh * NPOS * DHEAD;
    const unsigned short* vbase = vt + (size_t)bh * DHEAD * NPOS;

    for (int i = tid; i < 3969; i += 256) bias_s[i] = pos_emb[i * HEADS + h];

    const int i0 = qb * 64 + w * 16;
    bf16x8 aQ[2];
#pragma unroll
    for (int ks = 0; ks < 2; ++ks)
        aQ[ks] = *(const bf16x8*)(qbase + (size_t)(i0 + fr) * DHEAD + ks * 32 + fg * 8);

    // T14 staging addresses (pre-swizzled global source; linear LDS dest)
    const int dB0 = w * 1024 + lane * 16;          // bytes [0, 4096)
    const int dB1 = 4096 + w * 1024 + lane * 16;   // bytes [4096, 8192)
    const int row0 = dB0 >> 7, row1 = dB1 >> 7;
    const int col0 = ((dB0 & 127) ^ ((row0 & 7) << 4)) >> 1;
    const int col1 = ((dB1 & 127) ^ ((row1 & 7) << 4)) >> 1;

    // prologue: tile 0 -> registers
    bf16x8 rk0 = *(const bf16x8*)(kbase + (size_t)row0 * DHEAD + col0);
    bf16x8 rk1 = *(const bf16x8*)(kbase + (size_t)row1 * DHEAD + col1);
    bf16x8 rv0 = *(const bf16x8*)(vbase + (size_t)row0 * NPOS + col0);
    bf16x8 rv1 = *(const bf16x8*)(vbase + (size_t)row1 * NPOS + col1);

    float m[4], l[4];
    f32x4 o[4];
#pragma unroll
    for (int j = 0; j < 4; ++j) { m[j] = -1e30f; l[j] = 0.f; }
#pragma unroll
    for (int dn = 0; dn < 4; ++dn) o[dn] = {0.f, 0.f, 0.f, 0.f};

    __syncthreads();  // bias_s ready; kT/vT unused yet

    for (int t = 0; t < 16; ++t) {
        const int kv0 = t * 64;
        // write staged regs -> LDS
        *(bf16x8*)((char*)kT + dB0) = rk0;
        *(bf16x8*)((char*)kT + dB1) = rk1;
        *(bf16x8*)((char*)vT + dB0) = rv0;
        *(bf16x8*)((char*)vT + dB1) = rv1;
        // issue NEXT tile's global loads; latency hides under this tile's compute
        if (t < 15) {
            const int kv1 = kv0 + 64;
            rk0 = *(const bf16x8*)(kbase + (size_t)(kv1 + row0) * DHEAD + col0);
            rk1 = *(const bf16x8*)(kbase + (size_t)(kv1 + row1) * DHEAD + col1);
            rv0 = *(const bf16x8*)(vbase + (size_t)row0 * NPOS + kv1 + col0);
            rv1 = *(const bf16x8*)(vbase + (size_t)row1 * NPOS + kv1 + col1);
        }
        __syncthreads();  // staged writes visible to all waves

        f32x4 s[4];
#pragma unroll
        for (int nn = 0; nn < 4; ++nn) s[nn] = {0.f, 0.f, 0.f, 0.f};
#pragma unroll
        for (int ks = 0; ks < 2; ++ks) {
#pragma unroll
            for (int nn = 0; nn < 4; ++nn) {
                unsigned kb = (unsigned)(((nn * 16 + fr) * 64 + ks * 32 + fg * 8) * 2);
                kb ^= ((kb >> 7) & 7) << 4;
                bf16x8 bK = *(const bf16x8*)((const char*)kT + kb);
                s[nn] = __builtin_amdgcn_mfma_f32_16x16x32_bf16(aQ[ks], bK, s[nn], 0, 0, 0);
            }
        }
        // bias + tile max (row r = i0 + fg*4 + j, col = kv0 + nn*16 + fr)
        float tmax[4];
#pragma unroll
        for (int j = 0; j < 4; ++j) {
            int iglob = i0 + fg * 4 + j;
            int yi = iglob >> 5, xi = iglob & 31;
            float tm = -1e30f;
#pragma unroll
            for (int nn = 0; nn < 4; ++nn) {
                int jglob = kv0 + nn * 16 + fr;
                int yj = jglob >> 5, xj = jglob & 31;
                int bidx = (yi - yj + 31) * 63 + (xi - xj + 31);
                s[nn][j] += bias_s[bidx];
                tm = fmaxf(tm, s[nn][j]);
            }
            tm = fmaxf(tm, DPP_ROR(tm, 0x121));   // ror:1
            tm = fmaxf(tm, DPP_ROR(tm, 0x122));   // ror:2
            tm = fmaxf(tm, DPP_ROR(tm, 0x124));   // ror:4
            tm = fmaxf(tm, DPP_ROR(tm, 0x128));   // ror:8
            tmax[j] = tm;
        }
        // T13 defer-max: rescale only when some row max grows past THR
        bool grow = (tmax[0] > m[0] + THR) | (tmax[1] > m[1] + THR) |
                    (tmax[2] > m[2] + THR) | (tmax[3] > m[3] + THR);
        if (__any(grow)) {
#pragma unroll
            for (int j = 0; j < 4; ++j) {
                float pm = fmaxf(m[j], tmax[j]);
                float alpha = __expf(m[j] - pm);
                m[j] = pm;
                l[j] *= alpha;
#pragma unroll
                for (int dn = 0; dn < 4; ++dn) o[dn][j] *= alpha;
            }
        }
#pragma unroll
        for (int j = 0; j < 4; ++j) {
            float rsum = 0.f;
#pragma unroll
            for (int nn = 0; nn < 4; ++nn) {
                float pv = __expf(s[nn][j] - m[j]);
                s[nn][j] = pv;
                rsum += pv;
            }
            rsum += DPP_ROR(rsum, 0x121);
            rsum += DPP_ROR(rsum, 0x122);
            rsum += DPP_ROR(rsum, 0x124);
            rsum += DPP_ROR(rsum, 0x128);
            l[j] += rsum;
        }
        // P -> LDS (C/D layout -> A-operand layout), swizzled, wave-private
#pragma unroll
        for (int j = 0; j < 4; ++j) {
            int rrow = fg * 4 + j;
#pragma unroll
            for (int nn = 0; nn < 4; ++nn) {
                unsigned pb = (unsigned)((w * 16 + rrow) * 128 + (nn * 16 + fr) * 2);
                pb ^= ((pb >> 7) & 7) << 4;
                *(unsigned short*)((char*)pS + pb) = f2bf(s[nn][j]);
            }
        }
        // PV
#pragma unroll
        for (int ks = 0; ks < 2; ++ks) {
            unsigned pb = (unsigned)((w * 16 + fr) * 128 + (ks * 32 + fg * 8) * 2);
            pb ^= ((pb >> 7) & 7) << 4;
            bf16x8 aP = *(const bf16x8*)((const char*)pS + pb);
#pragma unroll
            for (int dn = 0; dn < 4; ++dn) {
                unsigned vb = (unsigned)(((dn * 16 + fr) * 64 + ks * 32 + fg * 8) * 2);
                vb ^= ((vb >> 7) & 7) << 4;
                bf16x8 bV = *(const bf16x8*)((const char*)vT + vb);
                o[dn] = __builtin_amdgcn_mfma_f32_16x16x32_bf16(aP, bV, o[dn], 0, 0, 0);
            }
        }
        __syncthreads();  // all waves done reading kT/vT before next overwrite
    }
    // epilogue: att_t[b][i][h*64+d] bf16
#pragma unroll
    for (int j = 0; j < 4; ++j) {
        float inv = 1.f / l[j];
        int iglob = i0 + fg * 4 + j;
        unsigned short* orow = att_t + ((size_t)b * NPOS + iglob) * INNER + h * DHEAD;
#pragma unroll
        for (int dn = 0; dn < 4; ++dn) orow[dn * 16 + fr] = f2bf(o[dn][j] * inv);
    }
}

// ---------------------------------------------------------------------------
extern "C" void kernel_launch(void* const* d_in, const int* in_sizes, int n_in,
                              void* d_out, int out_size, void* d_ws, size_t ws_size,
                              hipStream_t stream) {
    const float* x      = (const float*)d_in[0];
    const float* gamma  = (const float*)d_in[1];
    const float* w_qkv  = (const float*)d_in[2];
    const float* dw_w_q = (const float*)d_in[3];
    const float* dw_b_q = (const float*)d_in[4];
    const float* dw_w_k = (const float*)d_in[5];
    const float* dw_b_k = (const float*)d_in[6];
    const float* dw_w_v = (const float*)d_in[7];
    const float* dw_b_v = (const float*)d_in[8];
    const float* w_out  = (const float*)d_in[9];
    const float* pos_emb = (const float*)d_in[10];
    float* out = (float*)d_out;
    char* ws = (char*)d_ws;

    const size_t MB = 1024 * 1024;
    unsigned short* wqkv_bf = (unsigned short*)(ws + 0);              // 1.5MB
    unsigned short* wout_bf = (unsigned short*)(ws + 1536 * 512 * 2); // 0.5MB -> ends 2MB
    unsigned short* xn_t    = (unsigned short*)(ws + 2 * MB);         // 16MB [2,18)
    unsigned short* qkv     = (unsigned short*)(ws + 18 * MB);        // 48MB [18,66)
    unsigned short* qa      = (unsigned short*)(ws + 66 * MB);        // 16MB [66,82)
    unsigned short* kb      = (unsigned short*)(ws + 82 * MB);        // 16MB [82,98)
    unsigned short* vt      = (unsigned short*)(ws + 2 * MB);         // reuse xn (dead after K2)
    unsigned short* att_t   = (unsigned short*)(ws + 18 * MB);        // reuse qkv (dead after K3)

    cvt_kernel<<<dim3(768), dim3(256), 0, stream>>>(w_qkv, w_out, wqkv_bf, wout_bf);
    ln_kernel<<<dim3(512), dim3(256), 0, stream>>>(x, gamma, xn_t);
    gemm_bt<unsigned short><<<dim3(1536), dim3(256), 0, stream>>>(wqkv_bf, xn_t, qkv,
                                                                  1536, 1024, 512, 8, 12);
    dwconv_kernel<<<dim3(192, 16), dim3(256), 0, stream>>>(qkv, dw_w_q, dw_b_q, dw_w_k, dw_b_k,
                                                           dw_w_v, dw_b_v, qa, kb, vt);
    attn_kernel<<<dim3(16, 8, 16), dim3(256), 0, stream>>>(qa, kb, vt, pos_emb, att_t);
    gemm_bt64<<<dim3(16, 4, 16), dim3(256), 0, stream>>>(wout_bf, att_t, out, 512, 1024, 512);
}